// Round 1
// baseline (103.118 us; speedup 1.0000x reference)
//
#include <hip/hip_runtime.h>
#include <math.h>

#define NTILE 8
#define TS 64
#define T (NTILE * NTILE)
#define K 256
#define IMG_W (NTILE * TS)
#define PACK_STRIDE 12  // floats per packed gaussian slot (9 used, padded to 48B for alignment)

// Pass 1: gather + precompute per-(tile,k) packed gaussian data.
// slot = tile*K + k. Packed: [mux, muy, ea, eb, ed, op, cr, cg, cb]
// where (ea,eb,ed) are the coefficients of -0.5 * maha:
//   -0.5*maha = ea*dx^2 + eb*dx*dy + ed*dy^2
//   ia=d/det ib=-b/det ic=-c/det id=a/det  =>  ea=-0.5*d/det, eb=0.5*(b+c)/det, ed=-0.5*a/det
__global__ __launch_bounds__(256) void pack_kernel(
    const float* __restrict__ mu, const float* __restrict__ cov,
    const float* __restrict__ opacity, const float* __restrict__ color,
    const int* __restrict__ tile_idx, float* __restrict__ pack) {
  int slot = blockIdx.x * 256 + threadIdx.x;
  if (slot >= T * K) return;
  int n = tile_idx[slot];
  float a = cov[4 * n + 0];
  float b = cov[4 * n + 1];
  float c = cov[4 * n + 2];
  float d = cov[4 * n + 3];
  float det = fmaxf(a * d - b * c, 1e-6f);
  float rdet = 1.0f / det;
  float* g = pack + (size_t)slot * PACK_STRIDE;
  g[0] = mu[2 * n + 0];
  g[1] = mu[2 * n + 1];
  g[2] = -0.5f * d * rdet;
  g[3] = 0.5f * (b + c) * rdet;
  g[4] = -0.5f * a * rdet;
  g[5] = opacity[n];
  g[6] = color[3 * n + 0];
  g[7] = color[3 * n + 1];
  g[8] = color[3 * n + 2];
}

// Pass 2: one thread per pixel. Per-k data pointer depends only on blockIdx
// => wave-uniform => compiler emits s_load (scalar pipe, free vs VALU).
__global__ __launch_bounds__(256) void render_kernel(
    const float* __restrict__ pack, float* __restrict__ out) {
  int blk = blockIdx.x;
  int tile = blk >> 4;          // 16 chunks of 256 px per 64x64 tile
  int chunk = blk & 15;
  int p = chunk * 256 + threadIdx.x;  // pixel index within tile, p = ly*64+lx
  int ly = p >> 6;
  int lx = p & 63;
  int ty = tile >> 3;
  int tx = tile & 7;
  float px = (float)(tx * TS + lx) + 0.5f;
  float py = (float)(ty * TS + ly) + 0.5f;

  const float* g0 = pack + (size_t)tile * K * PACK_STRIDE;
  float accr = 0.0f, accg = 0.0f, accb = 0.0f, S = 0.0f;

#pragma unroll 4
  for (int k = 0; k < K; ++k) {
    const float* g = g0 + k * PACK_STRIDE;
    float mux = g[0], muy = g[1];
    float ea = g[2], eb = g[3], ed = g[4];
    float op = g[5], cr = g[6], cg = g[7], cb = g[8];
    float dx = px - mux;
    float dy = py - muy;
    float m = fmaf(ea * dx, dx, fmaf(eb * dx, dy, ed * dy * dy));  // -0.5*maha
    float prob = __expf(m);
    float alpha = fminf(fmaxf(op * prob, 0.01f), 0.99f);
    float w = alpha * (1.0f - S);  // trans = 1 - exclusive prefix sum
    accr = fmaf(w, cr, accr);
    accg = fmaf(w, cg, accg);
    accb = fmaf(w, cb, accb);
    S += alpha;
  }

  int y = ty * TS + ly;
  int x = tx * TS + lx;
  size_t o = ((size_t)y * IMG_W + x) * 3;
  out[o + 0] = accr;
  out[o + 1] = accg;
  out[o + 2] = accb;
}

// Fallback (only if ws_size is too small): stage packed data in LDS per block.
__global__ __launch_bounds__(256) void render_lds_kernel(
    const float* __restrict__ mu, const float* __restrict__ cov,
    const float* __restrict__ opacity, const float* __restrict__ color,
    const int* __restrict__ tile_idx, float* __restrict__ out) {
  __shared__ float4 sA[K];  // mux, muy, ea, eb
  __shared__ float4 sB[K];  // ed, op, cr, cg
  __shared__ float sC[K];   // cb
  int blk = blockIdx.x;
  int tile = blk >> 4;
  int t = threadIdx.x;
  {
    int n = tile_idx[tile * K + t];
    float a = cov[4 * n + 0];
    float b = cov[4 * n + 1];
    float c = cov[4 * n + 2];
    float d = cov[4 * n + 3];
    float det = fmaxf(a * d - b * c, 1e-6f);
    float rdet = 1.0f / det;
    sA[t] = make_float4(mu[2 * n], mu[2 * n + 1], -0.5f * d * rdet,
                        0.5f * (b + c) * rdet);
    sB[t] = make_float4(-0.5f * a * rdet, opacity[n], color[3 * n],
                        color[3 * n + 1]);
    sC[t] = color[3 * n + 2];
  }
  __syncthreads();

  int chunk = blk & 15;
  int p = chunk * 256 + t;
  int ly = p >> 6;
  int lx = p & 63;
  int ty = tile >> 3;
  int tx = tile & 7;
  float px = (float)(tx * TS + lx) + 0.5f;
  float py = (float)(ty * TS + ly) + 0.5f;
  float accr = 0.0f, accg = 0.0f, accb = 0.0f, S = 0.0f;

#pragma unroll 4
  for (int k = 0; k < K; ++k) {
    float4 A = sA[k];
    float4 B = sB[k];
    float cb = sC[k];
    float dx = px - A.x;
    float dy = py - A.y;
    float m = fmaf(A.z * dx, dx, fmaf(A.w * dx, dy, B.x * dy * dy));
    float prob = __expf(m);
    float alpha = fminf(fmaxf(B.y * prob, 0.01f), 0.99f);
    float w = alpha * (1.0f - S);
    accr = fmaf(w, B.z, accr);
    accg = fmaf(w, B.w, accg);
    accb = fmaf(w, cb, accb);
    S += alpha;
  }

  int y = ty * TS + ly;
  int x = tx * TS + lx;
  size_t o = ((size_t)y * IMG_W + x) * 3;
  out[o + 0] = accr;
  out[o + 1] = accg;
  out[o + 2] = accb;
}

extern "C" void kernel_launch(void* const* d_in, const int* in_sizes, int n_in,
                              void* d_out, int out_size, void* d_ws,
                              size_t ws_size, hipStream_t stream) {
  const float* mu = (const float*)d_in[0];
  const float* cov = (const float*)d_in[1];
  const float* opacity = (const float*)d_in[2];
  const float* color = (const float*)d_in[3];
  const int* tile_idx = (const int*)d_in[4];
  float* out = (float*)d_out;

  const size_t need = (size_t)T * K * PACK_STRIDE * sizeof(float);  // 768 KB
  const int n_blocks = T * ((TS * TS) / 256);                       // 1024

  if (ws_size >= need) {
    float* pack = (float*)d_ws;
    pack_kernel<<<(T * K + 255) / 256, 256, 0, stream>>>(mu, cov, opacity,
                                                         color, tile_idx, pack);
    render_kernel<<<n_blocks, 256, 0, stream>>>(pack, out);
  } else {
    render_lds_kernel<<<n_blocks, 256, 0, stream>>>(mu, cov, opacity, color,
                                                    tile_idx, out);
  }
}